// Round 1
// baseline (199.039 us; speedup 1.0000x reference)
//
#include <hip/hip_runtime.h>
#include <cstddef>

// TemporalConvTranspose2d: band-strided transpose conv, causal in time.
// x: (B, N_BAND_IN*D_IN, T) band-major channels (chan = s*D_IN + d_in), fp32
// W: (D_OUT, D_IN, K_BAND, K_T) fp32
// b: (D_OUT,) fp32
// out: (B, N_BAND_OUT*D_OUT, T) (chan = n*D_OUT + d_out), fp32
//
// Key identity: output band n gets contributions from (kb = 2j + (n&1),
// s = (n + 2j + (n&1) - 2)/2) for j in {0,1}, s clipped to [0, 32).
// Time: y[t] = sum_kt W[.., kt] * x[t - 2 + kt]  (causal, pad_t = 2).

#define D_IN_ 32
#define N_BAND_IN_ 32
#define D_OUT_ 32
#define K_BAND_ 4
#define K_T_ 3
#define T_ 1000
#define B_ 8
#define N_BAND_OUT_ 64

#define TT 256      // t-tile per block
#define THREADS 128 // each thread covers t and t+128

__global__ __launch_bounds__(THREADS)
void tct_kernel(const float* __restrict__ x,
                const float* __restrict__ W,
                const float* __restrict__ bias,
                float* __restrict__ out)
{
    __shared__ float Wl[2 * K_T_ * D_IN_ * D_OUT_]; // [j][kt][d_in][d_out]
    __shared__ float bl[D_OUT_];

    const int tid = threadIdx.x;
    const int tt0 = blockIdx.x * TT;
    const int n   = blockIdx.y;   // output band
    const int bb  = blockIdx.z;   // batch
    const int p   = n & 1;

    // Stage the two needed kb-planes of W, transposed so d_out is contiguous.
    for (int idx = tid; idx < 2 * K_T_ * D_IN_ * D_OUT_; idx += THREADS) {
        const int d_out = idx & 31;
        const int d_in  = (idx >> 5) & 31;
        const int rest  = idx >> 10;        // j*K_T + kt
        const int kt    = rest % K_T_;
        const int j     = rest / K_T_;
        const int kb    = 2 * j + p;
        Wl[idx] = W[((d_out * D_IN_ + d_in) * K_BAND_ + kb) * K_T_ + kt];
    }
    if (tid < D_OUT_) bl[tid] = bias[tid];
    __syncthreads();

    float acc0[D_OUT_], acc1[D_OUT_];
#pragma unroll
    for (int i = 0; i < D_OUT_; ++i) { acc0[i] = 0.f; acc1[i] = 0.f; }

    const int ta = tt0 + tid;
    const int tb = ta + THREADS;
    const bool va = (ta < T_);
    const bool vb = (tb < T_);

#pragma unroll
    for (int j = 0; j < 2; ++j) {
        const int s = (n + 2 * j + p - 2) >> 1;
        if (s < 0 || s >= N_BAND_IN_) continue;
        const float* xp = x + ((size_t)bb * N_BAND_IN_ * D_IN_ + (size_t)s * D_IN_) * T_;
        for (int d_in = 0; d_in < D_IN_; ++d_in) {
            const float* xr = xp + d_in * T_;
            float xa[3], xb[3];
#pragma unroll
            for (int kt = 0; kt < 3; ++kt) {
                const int tia = ta - 2 + kt;
                const int tib = tb - 2 + kt;
                xa[kt] = (tia >= 0 && tia < T_) ? xr[tia] : 0.f;
                xb[kt] = (tib >= 0 && tib < T_) ? xr[tib] : 0.f;
            }
#pragma unroll
            for (int kt = 0; kt < 3; ++kt) {
                const float4* w4 =
                    (const float4*)&Wl[((j * K_T_ + kt) * D_IN_ + d_in) * D_OUT_];
#pragma unroll
                for (int g = 0; g < 8; ++g) {
                    const float4 w = w4[g];
                    acc0[4 * g + 0] = fmaf(w.x, xa[kt], acc0[4 * g + 0]);
                    acc0[4 * g + 1] = fmaf(w.y, xa[kt], acc0[4 * g + 1]);
                    acc0[4 * g + 2] = fmaf(w.z, xa[kt], acc0[4 * g + 2]);
                    acc0[4 * g + 3] = fmaf(w.w, xa[kt], acc0[4 * g + 3]);
                    acc1[4 * g + 0] = fmaf(w.x, xb[kt], acc1[4 * g + 0]);
                    acc1[4 * g + 1] = fmaf(w.y, xb[kt], acc1[4 * g + 1]);
                    acc1[4 * g + 2] = fmaf(w.z, xb[kt], acc1[4 * g + 2]);
                    acc1[4 * g + 3] = fmaf(w.w, xb[kt], acc1[4 * g + 3]);
                }
            }
        }
    }

    float* op = out + ((size_t)bb * N_BAND_OUT_ + (size_t)n) * D_OUT_ * T_;
#pragma unroll
    for (int d = 0; d < D_OUT_; ++d) {
        const float bv = bl[d];
        if (va) op[d * T_ + ta] = acc0[d] + bv;
        if (vb) op[d * T_ + tb] = acc1[d] + bv;
    }
}

extern "C" void kernel_launch(void* const* d_in, const int* in_sizes, int n_in,
                              void* d_out, int out_size, void* d_ws, size_t ws_size,
                              hipStream_t stream) {
    const float* x    = (const float*)d_in[0];
    const float* W    = (const float*)d_in[1];
    const float* bias = (const float*)d_in[2];
    float* out = (float*)d_out;

    dim3 grid((T_ + TT - 1) / TT, N_BAND_OUT_, B_);
    dim3 block(THREADS);
    tct_kernel<<<grid, block, 0, stream>>>(x, W, bias, out);
}

// Round 3
// 159.389 us; speedup vs baseline: 1.2488x; 1.2488x over previous
//
#include <hip/hip_runtime.h>
#include <cstddef>

// TemporalConvTranspose2d: band-strided transpose conv, causal in time.
// x: (B, N_BAND_IN*D_IN, T) band-major (chan = s*D_IN + d_in), fp32
// W: (D_OUT, D_IN, K_BAND, K_T), b: (D_OUT,), out: (B, N_BAND_OUT*D_OUT, T)
//
// Output band n <- input bands s = (n + 2j + (n&1) - 2)>>1, kb = 2j+(n&1), j in {0,1}.
// Causal time: y[t] = sum_kt W[..,kt] * x[t-2+kt].
//
// R2 design: no LDS (W via scalar path), 4-wave blocks, wave owns 8 d_out,
// lane owns 4 consecutive t (float4 loads), W pre-transposed to
// [kb][kt][d_in][d_out] in d_ws so each wave reads one s_load_dwordx8 row.

#define D_IN_ 32
#define D_OUT_ 32
#define N_BI_ 32
#define N_BO_ 64
#define K_B_ 4
#define K_T_ 3
#define T_ 1000
#define B_ 8

#define WT_ELEMS (K_B_ * K_T_ * D_IN_ * D_OUT_)   // 12288 floats = 48 KiB

__global__ __launch_bounds__(256)
void wtrans_kernel(const float* __restrict__ W, float* __restrict__ Wt) {
    int idx = blockIdx.x * 256 + threadIdx.x;
    if (idx >= WT_ELEMS) return;
    int d_out = idx & 31;
    int d_in  = (idx >> 5) & 31;
    int kt    = (idx >> 10) % K_T_;
    int kb    = (idx >> 10) / K_T_;
    Wt[idx] = W[((d_out * D_IN_ + d_in) * K_B_ + kb) * K_T_ + kt];
}

template <bool USE_WT>
__global__ __launch_bounds__(256)
void tct_kernel(const float* __restrict__ x,
                const float* __restrict__ Wsrc,   // USE_WT ? Wt[kb][kt][d_in][d_out] : W
                const float* __restrict__ bias,
                float* __restrict__ out)
{
    const int lane = threadIdx.x & 63;
    const int wav  = __builtin_amdgcn_readfirstlane(threadIdx.x >> 6);
    const int dog  = wav * 8;                 // this wave's d_out base
    const int n    = blockIdx.y;              // output band
    const int bb   = blockIdx.z;              // batch
    const int p    = n & 1;

    int t0 = blockIdx.x * 256 + lane * 4;
    const bool act = (t0 < T_);
    if (!act) t0 = T_ - 4;                    // keep loads in-bounds; stores masked

    float acc[8][4];
#pragma unroll
    for (int i = 0; i < 8; ++i)
#pragma unroll
        for (int u = 0; u < 4; ++u) acc[i][u] = 0.f;

#pragma unroll
    for (int j = 0; j < 2; ++j) {
        const int s = (n + 2 * j + p - 2) >> 1;
        if (s < 0 || s >= N_BI_) continue;
        const int kb = 2 * j + p;
        const float* xband = x + (size_t)(bb * N_BI_ + s) * D_IN_ * T_;

        for (int d_in = 0; d_in < D_IN_; ++d_in) {
            const float* xr = xband + d_in * T_;
            const float4 xc = *(const float4*)(xr + t0);
            float4 xp = make_float4(0.f, 0.f, 0.f, 0.f);
            if (t0 > 0) xp = *(const float4*)(xr + t0 - 4);
            // xv[k] = x[t0 - 2 + k], k = 0..5
            const float xv[6] = {xp.z, xp.w, xc.x, xc.y, xc.z, xc.w};

#pragma unroll
            for (int kt = 0; kt < K_T_; ++kt) {
                float w[8];
                if (USE_WT) {
                    const int widx = __builtin_amdgcn_readfirstlane(
                        (((kb * K_T_ + kt) * D_IN_ + d_in) * D_OUT_) + dog);
#pragma unroll
                    for (int i = 0; i < 8; ++i) w[i] = Wsrc[widx + i];
                } else {
#pragma unroll
                    for (int i = 0; i < 8; ++i) {
                        const int widx = __builtin_amdgcn_readfirstlane(
                            (((dog + i) * D_IN_ + d_in) * K_B_ + kb) * K_T_ + kt);
                        w[i] = Wsrc[widx];
                    }
                }
#pragma unroll
                for (int i = 0; i < 8; ++i)
#pragma unroll
                    for (int u = 0; u < 4; ++u)
                        acc[i][u] = fmaf(w[i], xv[u + kt], acc[i][u]);
            }
        }
    }

    if (act) {
        float bv[8];
#pragma unroll
        for (int i = 0; i < 8; ++i) bv[i] = bias[dog + i];
        float* op = out + ((size_t)(bb * N_BO_ + n) * D_OUT_ + dog) * T_ + t0;
#pragma unroll
        for (int i = 0; i < 8; ++i) {
            float4 v;
            v.x = acc[i][0] + bv[i];
            v.y = acc[i][1] + bv[i];
            v.z = acc[i][2] + bv[i];
            v.w = acc[i][3] + bv[i];
            *(float4*)(op + (size_t)i * T_) = v;
        }
    }
}

extern "C" void kernel_launch(void* const* d_in, const int* in_sizes, int n_in,
                              void* d_out, int out_size, void* d_ws, size_t ws_size,
                              hipStream_t stream) {
    const float* x    = (const float*)d_in[0];
    const float* W    = (const float*)d_in[1];
    const float* bias = (const float*)d_in[2];
    float* out = (float*)d_out;

    dim3 grid((T_ + 255) / 256, N_BO_, B_);   // 4 x 64 x 8
    dim3 block(256);

    if (ws_size >= WT_ELEMS * sizeof(float)) {
        float* Wt = (float*)d_ws;
        wtrans_kernel<<<(WT_ELEMS + 255) / 256, 256, 0, stream>>>(W, Wt);
        tct_kernel<true><<<grid, block, 0, stream>>>(x, Wt, bias, out);
    } else {
        tct_kernel<false><<<grid, block, 0, stream>>>(x, W, bias, out);
    }
}

// Round 5
// 115.032 us; speedup vs baseline: 1.7303x; 1.3856x over previous
//
#include <hip/hip_runtime.h>
#include <cstddef>
#include <cstdint>

// TemporalConvTranspose2d as per-band GEMM on MFMA.
// x: (B, N_BI*D_IN, T) fp32, chan = s*D_IN + d_in
// W: (D_OUT, D_IN, K_B, K_T) fp32; b: (D_OUT,); out: (B, N_BO*D_OUT, T) fp32
// Band n = 2q+p: sources s_j = q + j + p - 1 with kb = 2j+p, j in {0,1}.
// Time causal: y[t] = sum_kt W[..,kt] * x[t-2+kt].
// GEMM: out[dout,t] = sum_k A[dout,k] B[k,t], k = (j*3+kt)*32 + d_in (K=192).
// MFMA 16x16x32 bf16, fp32 accum. A frags precomputed in d_ws (wprep).
// B frags: one ds_read_b128 from bf16 LDS laid out [band][t][d_in] with
// 16B-chunk XOR swizzle c' = c ^ (t&3) ^ ((t>>2)&3).

typedef __bf16 bf16x8 __attribute__((ext_vector_type(8)));
typedef __bf16 bf16x4 __attribute__((ext_vector_type(4)));
typedef float  f32x4  __attribute__((ext_vector_type(4)));

#define D_IN_ 32
#define D_OUT_ 32
#define N_BI_ 32
#define N_BO_ 64
#define K_B_ 4
#define K_T_ 3
#define T_ 1000
#define B_ 8

#define TT_ 256                  // t per block
#define XT_ 260                  // staged t rows: t0-4 .. t0+255
#define ROWB_ 64                 // bytes per LDS row (32 d_in * 2B)
#define WT_ELEMS (2 * 6 * 2 * 64 * 8)   // 12288 bf16 = 24576 B

__device__ __forceinline__ int swz(int t) { return (t & 3) ^ ((t >> 2) & 3); }

// Build A fragments: wt[((p*6+ks)*2+mt)*64 + lane] = 8 bf16, lane layout:
// dout = mt*16 + (l&15), d_in = (l>>4)*8 + r, (j,kt) = (ks/3, ks%3), kb = 2j+p.
__global__ __launch_bounds__(256)
void wprep(const float* __restrict__ W, __bf16* __restrict__ wt) {
    int idx = blockIdx.x * 256 + threadIdx.x;
    if (idx >= WT_ELEMS) return;
    int r = idx & 7, l = (idx >> 3) & 63, mt = (idx >> 9) & 1, rest = idx >> 10;
    int ks = rest % 6, p = rest / 6;
    int dout = mt * 16 + (l & 15), din = (l >> 4) * 8 + r;
    int j = ks / 3, kt = ks % 3, kb = 2 * j + p;
    wt[idx] = (__bf16)W[((dout * D_IN_ + din) * K_B_ + kb) * K_T_ + kt];
}

__global__ __launch_bounds__(256, 3)
void tct_mfma(const float* __restrict__ x, const __bf16* __restrict__ wt,
              const float* __restrict__ bias, float* __restrict__ out)
{
    __shared__ unsigned char xl[2 * XT_ * ROWB_];   // 33280 B

    const int tid = threadIdx.x;
    const int l   = tid & 63;
    const int w   = tid >> 6;          // wave id: t sub-chunk
    const int n   = blockIdx.y;
    const int bb  = blockIdx.z;
    const int p   = n & 1, q = n >> 1;
    const int t0  = blockIdx.x * TT_;
    const int tstart = t0 - 4;

    // ---- A fragments (block-constant weights) ----
    bf16x8 afrag[6][2];
    {
        const bf16x8* wp = (const bf16x8*)wt;
        const int base = p * 12 * 64;
#pragma unroll
        for (int ks = 0; ks < 6; ++ks)
#pragma unroll
            for (int mt = 0; mt < 2; ++mt)
                afrag[ks][mt] = wp[base + (ks * 2 + mt) * 64 + l];
    }

    // ---- stage x -> LDS bf16 [band j][t][d_in], swizzled, transposed ----
    {
        const int u  = tid & 15;       // si*8 + dg
        const int si = u >> 3;         // j
        const int dg = u & 7;          // d_in group of 4
        const int s  = q + si + p - 1;
        const bool bandok = (s >= 0) && (s < N_BI_);
        const float* xb = x + ((size_t)(bb * N_BI_ + (bandok ? s : 0)) * D_IN_ + dg * 4) * T_;
        unsigned char* lbase = xl + si * (XT_ * ROWB_);
        const int c = dg >> 1, h = dg & 1;
        for (int tq = (tid >> 4); tq < XT_ / 4; tq += 16) {
            const int tg = tstart + tq * 4;
            float vv[4][4];
            if (bandok && tg >= 0 && tg < T_) {
#pragma unroll
                for (int i = 0; i < 4; ++i)
                    *(float4*)&vv[i][0] = *(const float4*)(xb + (size_t)i * T_ + tg);
            } else {
#pragma unroll
                for (int i = 0; i < 4; ++i)
#pragma unroll
                    for (int k = 0; k < 4; ++k) vv[i][k] = 0.f;
            }
#pragma unroll
            for (int k = 0; k < 4; ++k) {
                const int t = tq * 4 + k;
                bf16x4 row;
                row[0] = (__bf16)vv[0][k];
                row[1] = (__bf16)vv[1][k];
                row[2] = (__bf16)vv[2][k];
                row[3] = (__bf16)vv[3][k];
                *(bf16x4*)(lbase + t * ROWB_ + ((c ^ swz(t)) << 4) + (h << 3)) = row;
            }
        }
    }
    __syncthreads();

    // ---- MFMA main loop: 4 Ntiles x 6 Ksteps x 2 Mtiles ----
    f32x4 acc[2][4];
#pragma unroll
    for (int mt = 0; mt < 2; ++mt)
#pragma unroll
        for (int nt = 0; nt < 4; ++nt)
#pragma unroll
            for (int r = 0; r < 4; ++r) acc[mt][nt][r] = 0.f;

    const int tl = (l & 15);
    const int cch = l >> 4;
#pragma unroll
    for (int nt = 0; nt < 4; ++nt) {
#pragma unroll
        for (int ks = 0; ks < 6; ++ks) {
            const int j  = ks / 3, kt = ks % 3;
            const int lt = w * 64 + nt * 16 + tl + kt + 2;
            const bf16x8 bfrag = *(const bf16x8*)(xl + j * (XT_ * ROWB_) + lt * ROWB_
                                                  + ((cch ^ swz(lt)) << 4));
            acc[0][nt] = __builtin_amdgcn_mfma_f32_16x16x32_bf16(afrag[ks][0], bfrag, acc[0][nt], 0, 0, 0);
            acc[1][nt] = __builtin_amdgcn_mfma_f32_16x16x32_bf16(afrag[ks][1], bfrag, acc[1][nt], 0, 0, 0);
        }
    }

    // ---- epilogue: C/D layout col=l&15 (t), row=(l>>4)*4+reg (dout) ----
    const int rbase = (l >> 4) * 4;
    float bv[2][4];
#pragma unroll
    for (int mt = 0; mt < 2; ++mt)
#pragma unroll
        for (int r = 0; r < 4; ++r) bv[mt][r] = bias[mt * 16 + rbase + r];

#pragma unroll
    for (int mt = 0; mt < 2; ++mt)
#pragma unroll
        for (int nt = 0; nt < 4; ++nt) {
            const int tcol = t0 + w * 64 + nt * 16 + tl;
            if (tcol < T_) {
                float* op = out + ((size_t)(bb * N_BO_ + n) * D_OUT_ + mt * 16 + rbase) * T_ + tcol;
#pragma unroll
                for (int r = 0; r < 4; ++r)
                    op[(size_t)r * T_] = acc[mt][nt][r] + bv[mt][r];
            }
        }
}

// fp32 fallback (verified R3 structure) if ws too small for wprep output.
__global__ __launch_bounds__(256)
void tct_fallback(const float* __restrict__ x, const float* __restrict__ W,
                  const float* __restrict__ bias, float* __restrict__ out)
{
    const int lane = threadIdx.x & 63;
    const int wav  = __builtin_amdgcn_readfirstlane(threadIdx.x >> 6);
    const int dog  = wav * 8;
    const int n    = blockIdx.y;
    const int bb   = blockIdx.z;
    const int p    = n & 1;

    int t0 = blockIdx.x * 256 + lane * 4;
    const bool act = (t0 < T_);
    if (!act) t0 = T_ - 4;

    float acc[8][4];
#pragma unroll
    for (int i = 0; i < 8; ++i)
#pragma unroll
        for (int u = 0; u < 4; ++u) acc[i][u] = 0.f;

#pragma unroll
    for (int j = 0; j < 2; ++j) {
        const int s = (n + 2 * j + p - 2) >> 1;
        if (s < 0 || s >= N_BI_) continue;
        const int kb = 2 * j + p;
        const float* xband = x + (size_t)(bb * N_BI_ + s) * D_IN_ * T_;
        for (int d_in = 0; d_in < D_IN_; ++d_in) {
            const float* xr = xband + d_in * T_;
            const float4 xc = *(const float4*)(xr + t0);
            float4 xp = make_float4(0.f, 0.f, 0.f, 0.f);
            if (t0 > 0) xp = *(const float4*)(xr + t0 - 4);
            const float xv[6] = {xp.z, xp.w, xc.x, xc.y, xc.z, xc.w};
#pragma unroll
            for (int kt = 0; kt < K_T_; ++kt) {
                float wv[8];
#pragma unroll
                for (int i = 0; i < 8; ++i) {
                    const int widx = __builtin_amdgcn_readfirstlane(
                        (((dog + i) * D_IN_ + d_in) * K_B_ + kb) * K_T_ + kt);
                    wv[i] = W[widx];
                }
#pragma unroll
                for (int i = 0; i < 8; ++i)
#pragma unroll
                    for (int u = 0; u < 4; ++u)
                        acc[i][u] = fmaf(wv[i], xv[u + kt], acc[i][u]);
            }
        }
    }
    if (act) {
        float bvv[8];
#pragma unroll
        for (int i = 0; i < 8; ++i) bvv[i] = bias[dog + i];
        float* op = out + ((size_t)(bb * N_BO_ + n) * D_OUT_ + dog) * T_ + t0;
#pragma unroll
        for (int i = 0; i < 8; ++i) {
            float4 v;
            v.x = acc[i][0] + bvv[i];
            v.y = acc[i][1] + bvv[i];
            v.z = acc[i][2] + bvv[i];
            v.w = acc[i][3] + bvv[i];
            *(float4*)(op + (size_t)i * T_) = v;
        }
    }
}

extern "C" void kernel_launch(void* const* d_in, const int* in_sizes, int n_in,
                              void* d_out, int out_size, void* d_ws, size_t ws_size,
                              hipStream_t stream) {
    const float* x    = (const float*)d_in[0];
    const float* W    = (const float*)d_in[1];
    const float* bias = (const float*)d_in[2];
    float* out = (float*)d_out;

    dim3 grid((T_ + TT_ - 1) / TT_, N_BO_, B_);   // 4 x 64 x 8
    dim3 block(256);

    if (ws_size >= (size_t)WT_ELEMS * sizeof(__bf16)) {
        __bf16* wt = (__bf16*)d_ws;
        wprep<<<(WT_ELEMS + 255) / 256, 256, 0, stream>>>(W, wt);
        tct_mfma<<<grid, block, 0, stream>>>(x, wt, bias, out);
    } else {
        tct_fallback<<<grid, block, 0, stream>>>(x, W, bias, out);
    }
}